// Round 1
// baseline (92479.681 us; speedup 1.0000x reference)
//
#include <hip/hip_runtime.h>

#define H    50
#define T    65536
#define NTHREADS 448

// ws layout (floats)
#define WC1_OFF 0        // 200*64
#define WC2_OFF 12800    // 200*128
#define BC1_OFF 38400    // 200
#define BC2_OFF 38600    // 200

// Prep: permute rows (orig r = gate*50+j  ->  new r' = j*4+gate) and pad cols.
// Wc1: 200 x 64  : cols 0..6 = W_ih1[:,0:7], col 7 = W_ih1[:,7] (err), 8..57 = W_hh1, 58..63 = 0
// Wc2: 200 x 128 : cols 0..49 = W_ih2, 50..99 = W_hh2, 100..127 = 0
__global__ void prep_kernel(const float* __restrict__ Wih1, const float* __restrict__ Whh1,
                            const float* __restrict__ bih1, const float* __restrict__ bhh1,
                            const float* __restrict__ Wih2, const float* __restrict__ Whh2,
                            const float* __restrict__ bih2, const float* __restrict__ bhh2,
                            float* __restrict__ ws) {
  int idx = blockIdx.x * blockDim.x + threadIdx.x;
  if (idx < 200 * 64) {
    int nr = idx >> 6, c = idx & 63;
    int j = nr >> 2, gate = nr & 3, r = gate * 50 + j;
    float v = 0.f;
    if (c < 8) v = Wih1[r * 8 + c];
    else if (c < 58) v = Whh1[r * 50 + (c - 8)];
    ws[WC1_OFF + idx] = v;
  }
  if (idx < 200 * 128) {
    int nr = idx >> 7, c = idx & 127;
    int j = nr >> 2, gate = nr & 3, r = gate * 50 + j;
    float v = 0.f;
    if (c < 50) v = Wih2[r * 50 + c];
    else if (c < 100) v = Whh2[r * 50 + (c - 50)];
    ws[WC2_OFF + idx] = v;
  }
  if (idx < 200) {
    int j = idx >> 2, gate = idx & 3, r = gate * 50 + j;
    ws[BC1_OFF + idx] = bih1[r] + bhh1[r];
    ws[BC2_OFF + idx] = bih2[r] + bhh2[r];
  }
}

__device__ __forceinline__ float sigm(float x) {
  return __builtin_amdgcn_rcpf(1.f + __expf(-x));
}
__device__ __forceinline__ float tanh_(float x) {
  return 1.f - 2.f * __builtin_amdgcn_rcpf(1.f + __expf(2.f * x));
}
// LDS-only barrier: no vmcnt drain, so global prefetch loads and y-stores
// pipeline across steps. "memory" clobber pins LDS op ordering at IR level.
__device__ __forceinline__ void bar() {
  asm volatile("s_waitcnt lgkmcnt(0)\n\ts_barrier" ::: "memory");
}

__launch_bounds__(NTHREADS)
__global__ void lstm_kernel(const float* __restrict__ xseq,
                            const float* __restrict__ ws,
                            const float* __restrict__ Wout,
                            const float* __restrict__ bout,
                            float* __restrict__ out) {
  // Double-buffered (parity = t&1) step-state in LDS.
  // AIN[par][0..6]=x_t  [7]=err(t-1)  [8..57]=h1(t-1)  [58..63]=0
  // CIN[par][0..49]=h1(t)  [50..99]=h2(t-1)  [100..127]=0
  __shared__ __align__(16) float AIN[2][64];
  __shared__ __align__(16) float CIN[2][128];
  __shared__ float ACT[2];

  const int tid = threadIdx.x;
  const float* Wc1 = ws + WC1_OFF;
  const float* Wc2 = ws + WC2_OFF;
  const float* bc1 = ws + BC1_OFF;
  const float* bc2 = ws + BC2_OFF;

  // zero all LDS (pads must be 0: poisoned garbage could be NaN, NaN*0=NaN)
  for (int i = tid; i < 2 * 64; i += NTHREADS) ((float*)AIN)[i] = 0.f;
  for (int i = tid; i < 2 * 128; i += NTHREADS) ((float*)CIN)[i] = 0.f;
  if (tid < 2) ACT[tid] = 0.f;

  const int g  = tid >> 2, p  = tid & 3;  // phase A: unit g, col-slice p (tid<200)
  const int g2 = tid >> 3, p2 = tid & 7;  // phase C: unit g2, col-slice p2 (tid<400)

  float wa1[4][16]; float b1[4];
  float wa2[4][16]; float b2[4];
  float c1 = 0.f, c2 = 0.f, err = 0.f, xr = 0.f, wo = 0.f, bo = 0.f;

  if (tid < 200) {
    #pragma unroll
    for (int k = 0; k < 4; k++) {
      const float4* src = (const float4*)&Wc1[(4 * g + k) * 64 + p * 16];
      #pragma unroll
      for (int q = 0; q < 4; q++) {
        float4 v = src[q];
        wa1[k][4*q+0] = v.x; wa1[k][4*q+1] = v.y; wa1[k][4*q+2] = v.z; wa1[k][4*q+3] = v.w;
      }
      b1[k] = bc1[4 * g + k];
    }
  }
  if (tid < 400) {
    #pragma unroll
    for (int k = 0; k < 4; k++) {
      const float4* src = (const float4*)&Wc2[(4 * g2 + k) * 128 + p2 * 16];
      #pragma unroll
      for (int q = 0; q < 4; q++) {
        float4 v = src[q];
        wa2[k][4*q+0] = v.x; wa2[k][4*q+1] = v.y; wa2[k][4*q+2] = v.z; wa2[k][4*q+3] = v.w;
      }
      b2[k] = bc2[4 * g2 + k];
    }
  }
  if (tid < 64) {
    wo = (tid < 50) ? Wout[tid] : 0.f;
    bo = bout[0];
  }
  // loader lanes: prefetch x rows two steps ahead (depth-2 pipeline)
  if (tid >= 400 && tid < 408) {
    int c = tid - 400;
    float v0 = xseq[c];             // row 0
    if (c < 7) AIN[0][c] = v0; else ACT[0] = v0;
    xr = xseq[8 + c];               // row 1 staged in regs
  }
  __syncthreads();

  auto step = [&](int t, int par) {
    // ---------------- Phase A: cell-1 gates + h1/c1 update ----------------
    if (tid < 200) {
      float ur[16];
      const float4* up = (const float4*)&AIN[par][p * 16];
      #pragma unroll
      for (int q = 0; q < 4; q++) {
        float4 v = up[q];
        ur[4*q+0] = v.x; ur[4*q+1] = v.y; ur[4*q+2] = v.z; ur[4*q+3] = v.w;
      }
      float a0 = 0.f, a1 = 0.f, a2 = 0.f, a3 = 0.f;
      #pragma unroll
      for (int j = 0; j < 16; j++) {
        a0 += wa1[0][j] * ur[j];
        a1 += wa1[1][j] * ur[j];
        a2 += wa1[2][j] * ur[j];
        a3 += wa1[3][j] * ur[j];
      }
      a0 += __shfl_xor(a0, 1); a0 += __shfl_xor(a0, 2);
      a1 += __shfl_xor(a1, 1); a1 += __shfl_xor(a1, 2);
      a2 += __shfl_xor(a2, 1); a2 += __shfl_xor(a2, 2);
      a3 += __shfl_xor(a3, 1); a3 += __shfl_xor(a3, 2);
      if (p == 0) {  // this lane owns unit g: rows 4g+{0,1,2,3} = i,f,g,o
        float gi = sigm (a0 + b1[0]);
        float gf = sigm (a1 + b1[1]);
        float gg = tanh_(a2 + b1[2]);
        float go = sigm (a3 + b1[3]);
        c1 = gf * c1 + gi * gg;
        float h1 = go * tanh_(c1);
        CIN[par][g]          = h1;  // for cell-2 this step
        AIN[par ^ 1][8 + g]  = h1;  // for cell-1 next step
      }
    }
    bar();
    // ---------------- Phase C: cell-2 gates + h2/c2 update + loader -------
    if (tid < 400) {
      float ur[16];
      const float4* up = (const float4*)&CIN[par][p2 * 16];
      #pragma unroll
      for (int q = 0; q < 4; q++) {
        float4 v = up[q];
        ur[4*q+0] = v.x; ur[4*q+1] = v.y; ur[4*q+2] = v.z; ur[4*q+3] = v.w;
      }
      float a0 = 0.f, a1 = 0.f, a2 = 0.f, a3 = 0.f;
      #pragma unroll
      for (int j = 0; j < 16; j++) {
        a0 += wa2[0][j] * ur[j];
        a1 += wa2[1][j] * ur[j];
        a2 += wa2[2][j] * ur[j];
        a3 += wa2[3][j] * ur[j];
      }
      a0 += __shfl_xor(a0, 1); a0 += __shfl_xor(a0, 2); a0 += __shfl_xor(a0, 4);
      a1 += __shfl_xor(a1, 1); a1 += __shfl_xor(a1, 2); a1 += __shfl_xor(a1, 4);
      a2 += __shfl_xor(a2, 1); a2 += __shfl_xor(a2, 2); a2 += __shfl_xor(a2, 4);
      a3 += __shfl_xor(a3, 1); a3 += __shfl_xor(a3, 2); a3 += __shfl_xor(a3, 4);
      if (p2 == 0) {  // owns unit g2
        float gi = sigm (a0 + b2[0]);
        float gf = sigm (a1 + b2[1]);
        float gg = tanh_(a2 + b2[2]);
        float go = sigm (a3 + b2[3]);
        c2 = gf * c2 + gi * gg;
        float h2 = go * tanh_(c2);
        CIN[par ^ 1][50 + g2] = h2;  // for y(t) and cell-2 next step
      }
    } else if (tid < 408) {
      int c = tid - 400;
      if (c < 7) AIN[par ^ 1][c] = xr; else ACT[par ^ 1] = xr;  // publish x(t+1)
      int nt = (t + 2 < T) ? t + 2 : T - 1;
      xr = xseq[nt * 8 + c];                                    // fetch x(t+2)
    }
    bar();
    // ---------------- Phase Y: y, out store, err update (wave 0) ----------
    if (tid < 64) {
      float v = CIN[par ^ 1][50 + tid] * wo;  // cols 100..113 are zero pad
      v += __shfl_xor(v, 1);  v += __shfl_xor(v, 2);  v += __shfl_xor(v, 4);
      v += __shfl_xor(v, 8);  v += __shfl_xor(v, 16); v += __shfl_xor(v, 32);
      if (tid == 0) {
        float y = v + bo;
        out[t] = y;                       // fire-and-forget (no vmcnt drain at bar)
        err = 0.9f * err + 0.1f * (ACT[par] - y);
        AIN[par ^ 1][7] = err;
      }
    }
    bar();
  };

  for (int t = 0; t < T; t += 2) {
    step(t, 0);
    step(t + 1, 1);
  }
}

extern "C" void kernel_launch(void* const* d_in, const int* in_sizes, int n_in,
                              void* d_out, int out_size, void* d_ws, size_t ws_size,
                              hipStream_t stream) {
  const float* xseq = (const float*)d_in[0];
  const float* Wih1 = (const float*)d_in[1];
  const float* Whh1 = (const float*)d_in[2];
  const float* bih1 = (const float*)d_in[3];
  const float* bhh1 = (const float*)d_in[4];
  const float* Wih2 = (const float*)d_in[5];
  const float* Whh2 = (const float*)d_in[6];
  const float* bih2 = (const float*)d_in[7];
  const float* bhh2 = (const float*)d_in[8];
  const float* Wout = (const float*)d_in[9];
  const float* bout = (const float*)d_in[10];
  float* ws = (float*)d_ws;

  prep_kernel<<<100, 256, 0, stream>>>(Wih1, Whh1, bih1, bhh1,
                                       Wih2, Whh2, bih2, bhh2, ws);
  lstm_kernel<<<1, NTHREADS, 0, stream>>>(xseq, ws, Wout, bout, (float*)d_out);
}

// Round 2
// 67205.096 us; speedup vs baseline: 1.3761x; 1.3761x over previous
//
#include <hip/hip_runtime.h>

#define H    50
#define T    65536
#define NTHREADS 448

// ws layout (floats) — logical dense layouts (LDS padding is applied at LDS
// level only; weight registers are sliced per 16 logical columns).
#define WC1_OFF 0        // 200*64
#define WC2_OFF 12800    // 200*128
#define BC1_OFF 38400    // 200
#define BC2_OFF 38600    // 200

// Prep: permute rows (orig r = gate*50+j  ->  new r' = j*4+gate) and pad cols.
// Wc1: 200 x 64  : cols 0..6 = W_ih1[:,0:7], col 7 = W_ih1[:,7] (err), 8..57 = W_hh1, 58..63 = 0
// Wc2: 200 x 128 : cols 0..49 = W_ih2, 50..99 = W_hh2, 100..127 = 0
__global__ void prep_kernel(const float* __restrict__ Wih1, const float* __restrict__ Whh1,
                            const float* __restrict__ bih1, const float* __restrict__ bhh1,
                            const float* __restrict__ Wih2, const float* __restrict__ Whh2,
                            const float* __restrict__ bih2, const float* __restrict__ bhh2,
                            float* __restrict__ ws) {
  int idx = blockIdx.x * blockDim.x + threadIdx.x;
  if (idx < 200 * 64) {
    int nr = idx >> 6, c = idx & 63;
    int j = nr >> 2, gate = nr & 3, r = gate * 50 + j;
    float v = 0.f;
    if (c < 8) v = Wih1[r * 8 + c];
    else if (c < 58) v = Whh1[r * 50 + (c - 8)];
    ws[WC1_OFF + idx] = v;
  }
  if (idx < 200 * 128) {
    int nr = idx >> 7, c = idx & 127;
    int j = nr >> 2, gate = nr & 3, r = gate * 50 + j;
    float v = 0.f;
    if (c < 50) v = Wih2[r * 50 + c];
    else if (c < 100) v = Whh2[r * 50 + (c - 50)];
    ws[WC2_OFF + idx] = v;
  }
  if (idx < 200) {
    int j = idx >> 2, gate = idx & 3, r = gate * 50 + j;
    ws[BC1_OFF + idx] = bih1[r] + bhh1[r];
    ws[BC2_OFF + idx] = bih2[r] + bhh2[r];
  }
}

__device__ __forceinline__ float sigm(float x) {
  return __builtin_amdgcn_rcpf(1.f + __expf(-x));
}
__device__ __forceinline__ float tanh_(float x) {
  return 1.f - 2.f * __builtin_amdgcn_rcpf(1.f + __expf(2.f * x));
}
// LDS-only barrier: no vmcnt drain, so global prefetch loads and y-stores
// pipeline across steps. "memory" clobber pins LDS op ordering at IR level.
__device__ __forceinline__ void bar() {
  asm volatile("s_waitcnt lgkmcnt(0)\n\ts_barrier" ::: "memory");
}

// DPP cross-lane add: x + x[lane ^ pattern], VALU pipe (no LDS latency).
// 0xB1 = quad_perm(1,0,3,2) = xor1 ; 0x4E = quad_perm(2,3,0,1) = xor2
// 0x141 = row_half_mirror (lane -> lane^7 within 8; after xor1+xor2 the value
//         is quad-uniform, so this completes an 8-lane reduce)
// 0x140 = row_mirror (lane -> lane^15 within 16; completes 16-lane reduce)
template<int CTRL>
__device__ __forceinline__ float dpp_add(float x) {
  int y = __builtin_amdgcn_mov_dpp(__float_as_int(x), CTRL, 0xF, 0xF, true);
  return x + __int_as_float(y);
}

// logical column -> padded LDS offset: chunks of 16 floats at stride 20
// (80 B, 16 B-aligned; chunk bank starts {0,20,8,28,16,4,24,12} - disjoint)
__device__ __forceinline__ int phys(int c) { return (c >> 4) * 20 + (c & 15); }

__launch_bounds__(NTHREADS, 2)   // 2 waves/EU min -> 256-VGPR budget: weights stay in regs
__global__ void lstm_kernel(const float* __restrict__ xseq,
                            const float* __restrict__ ws,
                            const float* __restrict__ Wout,
                            const float* __restrict__ bout,
                            float* __restrict__ out) {
  // Double-buffered (parity = t&1) step-state in LDS, chunk-padded (16->20).
  // AIN logical [0..6]=x_t [7]=err(t-1) [8..57]=h1(t-1) [58..63]=0   (4 chunks)
  // CIN logical [0..49]=h1(t) [50..99]=h2(t-1) [100..127]=0          (8 chunks)
  __shared__ __align__(16) float AIN[2][80];
  __shared__ __align__(16) float CIN[2][160];
  __shared__ float ACT[2];

  const int tid = threadIdx.x;
  const float* Wc1 = ws + WC1_OFF;
  const float* Wc2 = ws + WC2_OFF;
  const float* bc1 = ws + BC1_OFF;
  const float* bc2 = ws + BC2_OFF;

  // zero all LDS (pads must stay 0 forever; poison could be NaN)
  for (int i = tid; i < 2 * 80; i += NTHREADS) ((float*)AIN)[i] = 0.f;
  for (int i = tid; i < 2 * 160; i += NTHREADS) ((float*)CIN)[i] = 0.f;
  if (tid < 2) ACT[tid] = 0.f;

  const int g  = tid >> 2, p  = tid & 3;  // phase A: unit g, 16-col slice p (tid<200)
  const int g2 = tid >> 3, p2 = tid & 7;  // phase C: unit g2, 16-col slice p2 (tid<400)

  float wa1[4][16]; float b1[4];
  float wa2[4][16]; float b2[4];
  float c1 = 0.f, c2 = 0.f, err = 0.f, xr = 0.f, wo = 0.f, bo = 0.f;

  if (tid < 200) {
    #pragma unroll
    for (int k = 0; k < 4; k++) {
      const float4* src = (const float4*)&Wc1[(4 * g + k) * 64 + p * 16];
      #pragma unroll
      for (int q = 0; q < 4; q++) {
        float4 v = src[q];
        wa1[k][4*q+0] = v.x; wa1[k][4*q+1] = v.y; wa1[k][4*q+2] = v.z; wa1[k][4*q+3] = v.w;
      }
      b1[k] = bc1[4 * g + k];
    }
  }
  if (tid < 400) {
    #pragma unroll
    for (int k = 0; k < 4; k++) {
      const float4* src = (const float4*)&Wc2[(4 * g2 + k) * 128 + p2 * 16];
      #pragma unroll
      for (int q = 0; q < 4; q++) {
        float4 v = src[q];
        wa2[k][4*q+0] = v.x; wa2[k][4*q+1] = v.y; wa2[k][4*q+2] = v.z; wa2[k][4*q+3] = v.w;
      }
      b2[k] = bc2[4 * g2 + k];
    }
  }
  const int yoff = phys(50 + tid);   // phase-Y read slot (cols >99 never written -> 0)
  if (tid < 64) {
    wo = (tid < 50) ? Wout[tid] : 0.f;
    bo = bout[0];
  }
  // loader lanes: prefetch x rows two steps ahead (depth-2 pipeline)
  if (tid >= 400 && tid < 408) {
    int c = tid - 400;
    float v0 = xseq[c];             // row 0
    if (c < 7) AIN[0][c] = v0; else ACT[0] = v0;
    xr = xseq[8 + c];               // row 1 staged in regs
  }
  __syncthreads();

  auto step = [&](int t, int par) {
    // ---------------- Phase A: cell-1 gates + h1/c1 update ----------------
    if (tid < 200) {
      float ur[16];
      const float4* up = (const float4*)&AIN[par][p * 20];
      #pragma unroll
      for (int q = 0; q < 4; q++) {
        float4 v = up[q];
        ur[4*q+0] = v.x; ur[4*q+1] = v.y; ur[4*q+2] = v.z; ur[4*q+3] = v.w;
      }
      float a0 = 0.f, a1 = 0.f, a2 = 0.f, a3 = 0.f;
      #pragma unroll
      for (int j = 0; j < 16; j++) {
        a0 += wa1[0][j] * ur[j];
        a1 += wa1[1][j] * ur[j];
        a2 += wa1[2][j] * ur[j];
        a3 += wa1[3][j] * ur[j];
      }
      a0 = dpp_add<0xB1>(a0); a0 = dpp_add<0x4E>(a0);
      a1 = dpp_add<0xB1>(a1); a1 = dpp_add<0x4E>(a1);
      a2 = dpp_add<0xB1>(a2); a2 = dpp_add<0x4E>(a2);
      a3 = dpp_add<0xB1>(a3); a3 = dpp_add<0x4E>(a3);
      if (p == 0) {  // this lane owns unit g: rows 4g+{0,1,2,3} = i,f,g,o
        float gi = sigm (a0 + b1[0]);
        float gf = sigm (a1 + b1[1]);
        float gg = tanh_(a2 + b1[2]);
        float go = sigm (a3 + b1[3]);
        c1 = gf * c1 + gi * gg;
        float h1 = go * tanh_(c1);
        CIN[par][phys(g)]             = h1;  // for cell-2 this step
        AIN[par ^ 1][phys(8 + g)]     = h1;  // for cell-1 next step
      }
    }
    bar();
    // ---------------- Phase C: cell-2 gates + h2/c2 update + loader -------
    if (tid < 400) {
      float ur[16];
      const float4* up = (const float4*)&CIN[par][p2 * 20];
      #pragma unroll
      for (int q = 0; q < 4; q++) {
        float4 v = up[q];
        ur[4*q+0] = v.x; ur[4*q+1] = v.y; ur[4*q+2] = v.z; ur[4*q+3] = v.w;
      }
      float a0 = 0.f, a1 = 0.f, a2 = 0.f, a3 = 0.f;
      #pragma unroll
      for (int j = 0; j < 16; j++) {
        a0 += wa2[0][j] * ur[j];
        a1 += wa2[1][j] * ur[j];
        a2 += wa2[2][j] * ur[j];
        a3 += wa2[3][j] * ur[j];
      }
      a0 = dpp_add<0xB1>(a0); a0 = dpp_add<0x4E>(a0); a0 = dpp_add<0x141>(a0);
      a1 = dpp_add<0xB1>(a1); a1 = dpp_add<0x4E>(a1); a1 = dpp_add<0x141>(a1);
      a2 = dpp_add<0xB1>(a2); a2 = dpp_add<0x4E>(a2); a2 = dpp_add<0x141>(a2);
      a3 = dpp_add<0xB1>(a3); a3 = dpp_add<0x4E>(a3); a3 = dpp_add<0x141>(a3);
      if (p2 == 0) {  // owns unit g2
        float gi = sigm (a0 + b2[0]);
        float gf = sigm (a1 + b2[1]);
        float gg = tanh_(a2 + b2[2]);
        float go = sigm (a3 + b2[3]);
        c2 = gf * c2 + gi * gg;
        float h2 = go * tanh_(c2);
        CIN[par ^ 1][phys(50 + g2)] = h2;  // for y(t) and cell-2 next step
      }
    } else if (tid < 408) {
      int c = tid - 400;
      if (c < 7) AIN[par ^ 1][c] = xr; else ACT[par ^ 1] = xr;  // publish x(t+1)
      int nt = (t + 2 < T) ? t + 2 : T - 1;
      xr = xseq[nt * 8 + c];                                    // fetch x(t+2)
    }
    bar();
    // ---------------- Phase Y: y, out store, err update (wave 0) ----------
    if (tid < 64) {
      float v = CIN[par ^ 1][yoff] * wo;   // wo=0 for lanes >=50; pad slots stay 0
      v = dpp_add<0xB1>(v); v = dpp_add<0x4E>(v);
      v = dpp_add<0x141>(v); v = dpp_add<0x140>(v);
      v = v + __int_as_float(__builtin_amdgcn_ds_swizzle(__float_as_int(v), 0x401F)); // xor16
      float vlo = __int_as_float(__builtin_amdgcn_readlane(__float_as_int(v), 0));
      float vhi = __int_as_float(__builtin_amdgcn_readlane(__float_as_int(v), 32));
      if (tid == 0) {
        float y = vlo + vhi + bo;
        out[t] = y;                       // fire-and-forget (no vmcnt drain at bar)
        err = 0.9f * err + 0.1f * (ACT[par] - y);
        AIN[par ^ 1][7] = err;
      }
    }
    bar();
  };

  for (int t = 0; t < T; t += 2) {
    step(t, 0);
    step(t + 1, 1);
  }
}

extern "C" void kernel_launch(void* const* d_in, const int* in_sizes, int n_in,
                              void* d_out, int out_size, void* d_ws, size_t ws_size,
                              hipStream_t stream) {
  const float* xseq = (const float*)d_in[0];
  const float* Wih1 = (const float*)d_in[1];
  const float* Whh1 = (const float*)d_in[2];
  const float* bih1 = (const float*)d_in[3];
  const float* bhh1 = (const float*)d_in[4];
  const float* Wih2 = (const float*)d_in[5];
  const float* Whh2 = (const float*)d_in[6];
  const float* bih2 = (const float*)d_in[7];
  const float* bhh2 = (const float*)d_in[8];
  const float* Wout = (const float*)d_in[9];
  const float* bout = (const float*)d_in[10];
  float* ws = (float*)d_ws;

  prep_kernel<<<100, 256, 0, stream>>>(Wih1, Whh1, bih1, bhh1,
                                       Wih2, Whh2, bih2, bhh2, ws);
  lstm_kernel<<<1, NTHREADS, 0, stream>>>(xseq, ws, Wout, bout, (float*)d_out);
}